// Round 13
// baseline (267.606 us; speedup 1.0000x reference)
//
#include <hip/hip_runtime.h>
#include <stdint.h>

#define S_LEN 2048
#define D_MID 1024
#define N_HEADS 16
#define D_HEAD 64

typedef __attribute__((ext_vector_type(4))) float f32x4;
typedef __attribute__((ext_vector_type(8))) short bf16x8;

__device__ __forceinline__ unsigned short f2bf(float x) {
  unsigned int u = __builtin_bit_cast(unsigned int, x);
  u += 0x7fffu + ((u >> 16) & 1u);
  return (unsigned short)(u >> 16);
}
__device__ __forceinline__ float bf2f(unsigned short h) {
  unsigned int u = ((unsigned int)h) << 16;
  return __builtin_bit_cast(float, u);
}
__device__ __forceinline__ unsigned int pack2(float x, float y) {
  return (unsigned int)f2bf(x) | ((unsigned int)f2bf(y) << 16);
}
__device__ __forceinline__ bf16x8 pack8(f32x4 a, f32x4 b) {
  uint4 u;
  u.x = pack2(a.x, a.y); u.y = pack2(a.z, a.w);
  u.z = pack2(b.x, b.y); u.w = pack2(b.z, b.w);
  return __builtin_bit_cast(bf16x8, u);
}
// HW packed fp32->bf16 (RNE, identical rounding to f2bf) — GEMM staging only
__device__ __forceinline__ unsigned int cvtpk(float lo, float hi) {
  unsigned int r;
  asm("v_cvt_pk_bf16_f32 %0, %1, %2" : "=v"(r) : "v"(lo), "v"(hi));
  return r;
}

#define MFMA16(a, b, c) __builtin_amdgcn_mfma_f32_16x16x32_bf16((a), (b), (c), 0, 0, 0)

// ---------------------------------------------------------------------------
// cvt_w: fp32 -> bf16 for 4 weight matrices (1M elems each)
// ---------------------------------------------------------------------------
struct CvtP {
  const float* s[4];
  unsigned short* d[4];
};
__global__ __launch_bounds__(256) void cvt_w(CvtP P) {
  const int t = blockIdx.x * 256 + threadIdx.x;  // 0..524287
  const int seg = t >> 17;                       // 131072 threads/segment
  const int off = (t & 131071) * 8;
  const float* s = P.s[seg] + off;
  f32x4 x = *(const f32x4*)s, y = *(const f32x4*)(s + 4);
  uint4 u;
  u.x = cvtpk(x.x, x.y); u.y = cvtpk(x.z, x.w);
  u.z = cvtpk(y.x, y.y); u.w = cvtpk(y.z, y.w);
  *(uint4*)(P.d[seg] + off) = u;
}

// ---------------------------------------------------------------------------
// Projection GEMM: C = A(f32, MxK) * W^T(bf16, NxK) + bias, output bf16.
// 128x128 tile, BK=64, padded [128][72] LDS. [R8-verbatim]
// ---------------------------------------------------------------------------
struct ProjParams {
  const float* A[3];
  const unsigned short* W[3];
  const float* Bi[3];
  unsigned short* O[3];
};

__global__ __launch_bounds__(256) void gemm_proj(ProjParams P) {
  const int z = blockIdx.z;
  const float* __restrict__ A = P.A[z];
  const unsigned short* __restrict__ W = P.W[z];
  const float* __restrict__ bias = P.Bi[z];
  unsigned short* __restrict__ O = P.O[z];

  __shared__ __align__(16) unsigned short As[128][72];
  __shared__ __align__(16) unsigned short Bs[128][72];

  const int tid = threadIdx.x;
  const int lane = tid & 63, w = tid >> 6;
  const int wm = w >> 1, wn = w & 1;
  const int l15 = lane & 15, lhi = lane >> 4;
  const int m0 = blockIdx.y * 128, n0 = blockIdx.x * 128;
  const int sr = tid >> 1, sc = (tid & 1) * 32;

  f32x4 acc[4][4] = {};

  for (int k0 = 0; k0 < D_MID; k0 += 64) {
    __syncthreads();
    {
      const float* a = A + (size_t)(m0 + sr) * D_MID + k0 + sc;
      const unsigned short* b = W + (size_t)(n0 + sr) * D_MID + k0 + sc;
#pragma unroll
      for (int q = 0; q < 4; ++q) {
        f32x4 x = ((const f32x4*)a)[2 * q];
        f32x4 y = ((const f32x4*)a)[2 * q + 1];
        uint4 u;
        u.x = cvtpk(x.x, x.y); u.y = cvtpk(x.z, x.w);
        u.z = cvtpk(y.x, y.y); u.w = cvtpk(y.z, y.w);
        *(uint4*)&As[sr][sc + q * 8] = u;
        *(uint4*)&Bs[sr][sc + q * 8] = ((const uint4*)b)[q];
      }
    }
    __syncthreads();

    bf16x8 af[4][2], bfr[4][2];
#pragma unroll
    for (int a2 = 0; a2 < 4; ++a2) {
      af[a2][0] = *(const bf16x8*)&As[wm * 64 + a2 * 16 + l15][lhi * 8];
      af[a2][1] = *(const bf16x8*)&As[wm * 64 + a2 * 16 + l15][32 + lhi * 8];
      bfr[a2][0] = *(const bf16x8*)&Bs[wn * 64 + a2 * 16 + l15][lhi * 8];
      bfr[a2][1] = *(const bf16x8*)&Bs[wn * 64 + a2 * 16 + l15][32 + lhi * 8];
    }
#pragma unroll
    for (int a2 = 0; a2 < 4; ++a2)
#pragma unroll
      for (int b2 = 0; b2 < 4; ++b2) {
        acc[a2][b2] = MFMA16(af[a2][0], bfr[b2][0], acc[a2][b2]);
        acc[a2][b2] = MFMA16(af[a2][1], bfr[b2][1], acc[a2][b2]);
      }
  }

#pragma unroll
  for (int a2 = 0; a2 < 4; ++a2)
#pragma unroll
    for (int b2 = 0; b2 < 4; ++b2) {
      const int col = n0 + wn * 64 + b2 * 16 + l15;
      const float bv = bias[col];
#pragma unroll
      for (int j = 0; j < 4; ++j) {
        const int row = m0 + wm * 64 + a2 * 16 + lhi * 4 + j;
        O[(size_t)row * D_MID + col] = f2bf(acc[a2][b2][j] + bv);
      }
    }
}

// ---------------------------------------------------------------------------
// Output GEMM: preLN = ctx(f32, MxK) * wo^T(bf16, NxK) + bo + Q (residual).
// [R8-verbatim]
// ---------------------------------------------------------------------------
__global__ __launch_bounds__(256) void gemm_out(
    const float* __restrict__ Actx, const unsigned short* __restrict__ W,
    const float* __restrict__ bias, const float* __restrict__ resid,
    float* __restrict__ Of) {
  __shared__ __align__(16) unsigned short As[128][72];
  __shared__ __align__(16) unsigned short Bs[128][72];

  const int tid = threadIdx.x;
  const int lane = tid & 63, w = tid >> 6;
  const int wm = w >> 1, wn = w & 1;
  const int l15 = lane & 15, lhi = lane >> 4;
  const int m0 = blockIdx.y * 128, n0 = blockIdx.x * 128;
  const int sr = tid >> 1, sc = (tid & 1) * 32;

  f32x4 acc[4][4] = {};

  for (int k0 = 0; k0 < D_MID; k0 += 64) {
    __syncthreads();
    {
      const float* a = Actx + (size_t)(m0 + sr) * D_MID + k0 + sc;
      const unsigned short* b = W + (size_t)(n0 + sr) * D_MID + k0 + sc;
#pragma unroll
      for (int q = 0; q < 4; ++q) {
        f32x4 x = ((const f32x4*)a)[2 * q];
        f32x4 y = ((const f32x4*)a)[2 * q + 1];
        uint4 u;
        u.x = cvtpk(x.x, x.y); u.y = cvtpk(x.z, x.w);
        u.z = cvtpk(y.x, y.y); u.w = cvtpk(y.z, y.w);
        *(uint4*)&As[sr][sc + q * 8] = u;
        *(uint4*)&Bs[sr][sc + q * 8] = ((const uint4*)b)[q];
      }
    }
    __syncthreads();

    bf16x8 af[4][2], bfr[4][2];
#pragma unroll
    for (int a2 = 0; a2 < 4; ++a2) {
      af[a2][0] = *(const bf16x8*)&As[wm * 64 + a2 * 16 + l15][lhi * 8];
      af[a2][1] = *(const bf16x8*)&As[wm * 64 + a2 * 16 + l15][32 + lhi * 8];
      bfr[a2][0] = *(const bf16x8*)&Bs[wn * 64 + a2 * 16 + l15][lhi * 8];
      bfr[a2][1] = *(const bf16x8*)&Bs[wn * 64 + a2 * 16 + l15][32 + lhi * 8];
    }
#pragma unroll
    for (int a2 = 0; a2 < 4; ++a2)
#pragma unroll
      for (int b2 = 0; b2 < 4; ++b2) {
        acc[a2][b2] = MFMA16(af[a2][0], bfr[b2][0], acc[a2][b2]);
        acc[a2][b2] = MFMA16(af[a2][1], bfr[b2][1], acc[a2][b2]);
      }
  }

#pragma unroll
  for (int a2 = 0; a2 < 4; ++a2)
#pragma unroll
    for (int b2 = 0; b2 < 4; ++b2) {
      const int col = n0 + wn * 64 + b2 * 16 + l15;
      const float bv = bias[col];
#pragma unroll
      for (int j = 0; j < 4; ++j) {
        const int row = m0 + wm * 64 + a2 * 16 + lhi * 4 + j;
        Of[(size_t)row * D_MID + col] =
            acc[a2][b2][j] + bv + resid[(size_t)row * D_MID + col];
      }
    }
}

// ---------------------------------------------------------------------------
// bf16 transpose: v[2048][1024] -> vt[1024][2048]
// ---------------------------------------------------------------------------
__global__ __launch_bounds__(256) void transpose_to_vbt(
    const unsigned short* __restrict__ v, unsigned short* __restrict__ vt) {
  __shared__ __align__(16) unsigned short t[64][72];
  const int tid = threadIdx.x;
  const int bs = blockIdx.x * 64;
  const int bd = blockIdx.y * 64;
  {
    const int r = tid >> 2, c = (tid & 3) * 16;
    const unsigned short* src = v + (size_t)(bs + r) * D_MID + bd + c;
    *(uint4*)&t[r][c] = *(const uint4*)src;
    *(uint4*)&t[r][c + 8] = *(const uint4*)(src + 8);
  }
  __syncthreads();
  {
    const int d = tid >> 2, c = (tid & 3) * 16;
    unsigned int u[8];
#pragma unroll
    for (int jj = 0; jj < 8; ++jj)
      u[jj] = (unsigned int)t[c + 2 * jj][d] | ((unsigned int)t[c + 2 * jj + 1][d] << 16);
    uint4 w0, w1;
    w0.x = u[0]; w0.y = u[1]; w0.z = u[2]; w0.w = u[3];
    w1.x = u[4]; w1.y = u[5]; w1.z = u[6]; w1.w = u[7];
    unsigned short* dst = vt + (size_t)(bd + d) * S_LEN + bs + c;
    *(uint4*)dst = w0;
    *(uint4*)(dst + 8) = w1;
  }
}

// ---------------------------------------------------------------------------
// Mask -> keep-bitmask uint64[2048][32]  (bit k = attend). Auto-detect dtype.
// ---------------------------------------------------------------------------
__global__ __launch_bounds__(256) void pack_mask(const void* __restrict__ maskp,
                                                 unsigned long long* __restrict__ bits) {
  __shared__ int s_m32;
  if (threadIdx.x == 0) s_m32 = 1;
  __syncthreads();
  {
    const unsigned char* m8d = (const unsigned char*)maskp;
    bool nz = false;
    for (int i = threadIdx.x; i < 4096; i += 256)
      if (i & 3) nz |= (m8d[i] != 0);
    if (nz) s_m32 = 0;  // benign race: all writers store 0
  }
  __syncthreads();

  const int wi = blockIdx.x * 256 + threadIdx.x;  // 0..65535
  const int row = wi >> 5, chunk = wi & 31;
  unsigned long long keep = 0ull;
  if (s_m32) {
    const int* mi = (const int*)maskp + (size_t)row * S_LEN + chunk * 64;
#pragma unroll
    for (int q = 0; q < 16; ++q) {
      int4 v = ((const int4*)mi)[q];
      const int b = q * 4;
      if (!v.x) keep |= 1ull << b;
      if (!v.y) keep |= 1ull << (b + 1);
      if (!v.z) keep |= 1ull << (b + 2);
      if (!v.w) keep |= 1ull << (b + 3);
    }
  } else {
    const unsigned char* p = (const unsigned char*)maskp + (size_t)row * S_LEN + chunk * 64;
    union { uint4 v[4]; unsigned char c[64]; } u;
#pragma unroll
    for (int q = 0; q < 4; ++q) u.v[q] = ((const uint4*)p)[q];
#pragma unroll
    for (int b = 0; b < 64; ++b)
      if (!u.c[b]) keep |= 1ull << b;
  }
  bits[wi] = keep;
}

// ---------------------------------------------------------------------------
// lsum: LDS-free, barrier-free. K fragments read directly from the
// L2-resident kbuf panel (wave-coalesced: 4 lhi-groups jointly cover one
// 64B line per K row). 2048 blocks -> 8 blocks/CU, up to 32 waves/CU TLP.
// ---------------------------------------------------------------------------
__global__ __launch_bounds__(256) void lsum_kernel(
    const unsigned short* __restrict__ qb, const unsigned short* __restrict__ kb,
    const unsigned long long* __restrict__ bits, float* __restrict__ lpart) {
  const int bid = blockIdx.x;
  const int head = bid & 15;
  const int r = bid >> 4;  // 0..127
  const int q0 = (r & 31) * 64;
  const int kc = r >> 5;  // 0..3
  const int k0 = kc * (S_LEN / 4);

  const int tid = threadIdx.x;
  const int lane = tid & 63, w = tid >> 6;
  const int l15 = lane & 15, lhi = lane >> 4;

  bf16x8 aq[2];
  {
    const unsigned short* qp =
        qb + (size_t)(q0 + w * 16 + l15) * D_MID + head * D_HEAD + lhi * 8;
    aq[0] = *(const bf16x8*)qp;
    aq[1] = *(const bf16x8*)(qp + 32);
  }

  float plrow[4] = {0.f, 0.f, 0.f, 0.f};
  const unsigned short* kbase = kb + head * D_HEAD + lhi * 8;

  for (int kt = k0; kt < k0 + S_LEN / 4; kt += 64) {
    f32x4 sacc[4];
#pragma unroll
    for (int a = 0; a < 4; ++a) {
      const unsigned short* kp = kbase + (size_t)(kt + a * 16 + l15) * D_MID;
      bf16x8 b0 = *(const bf16x8*)kp;
      bf16x8 b1 = *(const bf16x8*)(kp + 32);
      f32x4 t2 = {0.f, 0.f, 0.f, 0.f};
      t2 = MFMA16(aq[0], b0, t2);
      t2 = MFMA16(aq[1], b1, t2);
      sacc[a] = t2;
    }

#pragma unroll
    for (int j = 0; j < 4; ++j) {
      const int qg = q0 + w * 16 + lhi * 4 + j;
      const unsigned long long w64 = bits[(size_t)qg * 32 + (kt >> 6)];
#pragma unroll
      for (int a = 0; a < 4; ++a) {
        const float keep = (float)((w64 >> (a * 16 + l15)) & 1ull);
        plrow[j] += __expf(sacc[a][j] * 0.125f) * keep;
      }
    }
  }

#pragma unroll
  for (int j = 0; j < 4; ++j) {
    float ts = plrow[j];
#pragma unroll
    for (int off = 1; off < 16; off <<= 1) ts += __shfl_xor(ts, off);
    plrow[j] = ts;
  }
  if (l15 == 0) {
#pragma unroll
    for (int j = 0; j < 4; ++j) {
      const int qg = q0 + w * 16 + lhi * 4 + j;
      lpart[((size_t)kc * N_HEADS + head) * S_LEN + qg] = plrow[j];
    }
  }
}

__global__ __launch_bounds__(256) void lcombine(const float* __restrict__ lpart,
                                                float* __restrict__ linv) {
  const int i = blockIdx.x * 256 + threadIdx.x;  // 0..32767
  const float s = lpart[i] + lpart[32768 + i] + lpart[65536 + i] + lpart[98304 + i];
  linv[i] = (s > 0.f) ? 1.f / s : 0.f;
}

// ---------------------------------------------------------------------------
// attn_main [R8-verbatim]: single pass, normalized P write (fp32 LDS -> nt
// dwordx4 stores) + PV. Reg-prefetch K/V. k-split nkc=2, bf16 ctx partials.
// ---------------------------------------------------------------------------
__global__ __launch_bounds__(256) void attn_main(
    const unsigned short* __restrict__ qb, const unsigned short* __restrict__ kb,
    const unsigned short* __restrict__ vbt, const unsigned long long* __restrict__ bits,
    const float* __restrict__ linv, float* __restrict__ attn_out,
    unsigned short* __restrict__ ctxp) {
  const int bid = blockIdx.x;
  const int head = bid & 15;
  const int r = bid >> 4;
  const int q0 = (r & 31) * 64;
  const int kc = r >> 5;               // 0..1
  const int kspan = S_LEN / 2;
  const int k_begin = kc * kspan;

  const int tid = threadIdx.x;
  const int lane = tid & 63, w = tid >> 6;
  const int l15 = lane & 15, lhi = lane >> 4;

  __shared__ __align__(16) unsigned short Kt[64][72];  // [key][dk]
  __shared__ __align__(16) unsigned short Vt[64][72];  // [d][key]
  __shared__ __align__(16) float PF[4][16][68];        // per-wave P (fp32)

  bf16x8 aq[2];
  float li[4];
  {
    const int qrow = q0 + w * 16 + l15;
    const unsigned short* qp = qb + (size_t)qrow * D_MID + head * D_HEAD + lhi * 8;
    aq[0] = *(const bf16x8*)qp;
    aq[1] = *(const bf16x8*)(qp + 32);
#pragma unroll
    for (int j = 0; j < 4; ++j)
      li[j] = linv[head * S_LEN + q0 + w * 16 + lhi * 4 + j];
  }

  f32x4 cacc[4] = {};
  const int sk = tid >> 2, sc = (tid & 3) * 16;
  const int ntiles = kspan / 64;

  uint4 kr0, kr1, vr0, vr1;
  {
    const unsigned short* srck = kb + (size_t)(k_begin + sk) * D_MID + head * D_HEAD + sc;
    kr0 = *(const uint4*)srck;
    kr1 = *(const uint4*)(srck + 8);
    const unsigned short* srcv = vbt + (size_t)(head * D_HEAD + sk) * S_LEN + k_begin + sc;
    vr0 = *(const uint4*)srcv;
    vr1 = *(const uint4*)(srcv + 8);
  }

  for (int t = 0; t < ntiles; ++t) {
    const int kt = k_begin + t * 64;
    __syncthreads();
    *(uint4*)&Kt[sk][sc] = kr0;
    *(uint4*)&Kt[sk][sc + 8] = kr1;
    *(uint4*)&Vt[sk][sc] = vr0;
    *(uint4*)&Vt[sk][sc + 8] = vr1;
    __syncthreads();
    if (t + 1 < ntiles) {
      const int kn = kt + 64;
      const unsigned short* srck = kb + (size_t)(kn + sk) * D_MID + head * D_HEAD + sc;
      kr0 = *(const uint4*)srck;
      kr1 = *(const uint4*)(srck + 8);
      const unsigned short* srcv = vbt + (size_t)(head * D_HEAD + sk) * S_LEN + kn + sc;
      vr0 = *(const uint4*)srcv;
      vr1 = *(const uint4*)(srcv + 8);
    }

    f32x4 sacc[4];
#pragma unroll
    for (int a = 0; a < 4; ++a) {
      bf16x8 b0 = *(const bf16x8*)&Kt[a * 16 + l15][lhi * 8];
      bf16x8 b1 = *(const bf16x8*)&Kt[a * 16 + l15][32 + lhi * 8];
      f32x4 t2 = {0.f, 0.f, 0.f, 0.f};
      t2 = MFMA16(aq[0], b0, t2);
      t2 = MFMA16(aq[1], b1, t2);
      sacc[a] = t2;
    }

    // p -> PF (fp32, wave-local)
#pragma unroll
    for (int j = 0; j < 4; ++j) {
      const int qg = q0 + w * 16 + lhi * 4 + j;
      const unsigned long long w64 = bits[(size_t)qg * 32 + (kt >> 6)];
#pragma unroll
      for (int a = 0; a < 4; ++a) {
        const float keep = (float)((w64 >> (a * 16 + l15)) & 1ull);
        PF[w][lhi * 4 + j][a * 16 + l15] = __expf(sacc[a][j] * 0.125f) * keep * li[j];
      }
    }

    // coalesced nt stores: 4x dwordx4 per lane, 256B per 16-lane group
    {
      float* abase = attn_out + (size_t)head * S_LEN * S_LEN +
                     (size_t)(q0 + w * 16) * S_LEN + kt;
#pragma unroll
      for (int g = 0; g < 4; ++g) {
        const int row = g * 4 + lhi;
        f32x4 v = *(const f32x4*)&PF[w][row][l15 * 4];
        __builtin_nontemporal_store(v, (f32x4*)(abase + (size_t)row * S_LEN + l15 * 4));
      }
    }

    // PV: rebuild bf16 A-fragments from PF (same rounding as before)
    bf16x8 pa0 = pack8(*(const f32x4*)&PF[w][l15][lhi * 8],
                       *(const f32x4*)&PF[w][l15][lhi * 8 + 4]);
    bf16x8 pa1 = pack8(*(const f32x4*)&PF[w][l15][32 + lhi * 8],
                       *(const f32x4*)&PF[w][l15][36 + lhi * 8]);
#pragma unroll
    for (int n = 0; n < 4; ++n) {
      bf16x8 v0 = *(const bf16x8*)&Vt[n * 16 + l15][lhi * 8];
      bf16x8 v1 = *(const bf16x8*)&Vt[n * 16 + l15][32 + lhi * 8];
      cacc[n] = MFMA16(pa0, v0, cacc[n]);
      cacc[n] = MFMA16(pa1, v1, cacc[n]);
    }
  }

  unsigned short* cp = ctxp + (size_t)kc * S_LEN * D_MID;
#pragma unroll
  for (int n = 0; n < 4; ++n)
#pragma unroll
    for (int j = 0; j < 4; ++j) {
      const int qg = q0 + w * 16 + lhi * 4 + j;
      const int col = head * D_HEAD + n * 16 + l15;
      cp[(size_t)qg * D_MID + col] = f2bf(cacc[n][j]);
    }
}

// ---------------------------------------------------------------------------
// ctx_reduce: ctx2(fp32, d_out) = sum of bf16 partials
// ---------------------------------------------------------------------------
__global__ __launch_bounds__(256) void ctx_reduce(const unsigned short* __restrict__ ctxp,
                                                  float* __restrict__ ctx2) {
  const int i = blockIdx.x * 256 + threadIdx.x;  // over 2M/4 ushort4
  ushort4 a = ((const ushort4*)ctxp)[i];
  ushort4 b = ((const ushort4*)(ctxp + (size_t)S_LEN * D_MID))[i];
  float4 o;
  o.x = bf2f(a.x) + bf2f(b.x);
  o.y = bf2f(a.y) + bf2f(b.y);
  o.z = bf2f(a.z) + bf2f(b.z);
  o.w = bf2f(a.w) + bf2f(b.w);
  ((float4*)ctx2)[i] = o;
}

// ---------------------------------------------------------------------------
// Row LayerNorm
// ---------------------------------------------------------------------------
__global__ __launch_bounds__(256) void layernorm_k(
    const float* __restrict__ x, const float* __restrict__ gamma,
    const float* __restrict__ beta, float* __restrict__ out) {
  const int row = blockIdx.x;
  const int tid = threadIdx.x;
  float4 v = ((const float4*)(x + (size_t)row * D_MID))[tid];
  float s = v.x + v.y + v.z + v.w;
  float s2 = v.x * v.x + v.y * v.y + v.z * v.z + v.w * v.w;
#pragma unroll
  for (int off = 1; off < 64; off <<= 1) {
    s += __shfl_xor(s, off);
    s2 += __shfl_xor(s2, off);
  }
  __shared__ float ps[4], ps2[4];
  const int w = tid >> 6;
  if ((tid & 63) == 0) { ps[w] = s; ps2[w] = s2; }
  __syncthreads();
  s = ps[0] + ps[1] + ps[2] + ps[3];
  s2 = ps2[0] + ps2[1] + ps2[2] + ps2[3];
  const float mu = s * (1.0f / D_MID);
  const float var = s2 * (1.0f / D_MID) - mu * mu;
  const float inv = rsqrtf(var + 1e-5f);
  float4 g = ((const float4*)gamma)[tid];
  float4 b = ((const float4*)beta)[tid];
  float4 o;
  o.x = (v.x - mu) * inv * g.x + b.x;
  o.y = (v.y - mu) * inv * g.y + b.y;
  o.z = (v.z - mu) * inv * g.z + b.z;
  o.w = (v.w - mu) * inv * g.w + b.w;
  ((float4*)(out + (size_t)row * D_MID))[tid] = o;
}

// ---------------------------------------------------------------------------
extern "C" void kernel_launch(void* const* d_in, const int* in_sizes, int n_in,
                              void* d_out, int out_size, void* d_ws, size_t ws_size,
                              hipStream_t stream) {
  (void)in_sizes; (void)n_in; (void)out_size; (void)ws_size;
  const float* Q = (const float*)d_in[0];
  const float* K = (const float*)d_in[1];
  const float* V = (const float*)d_in[2];
  const void* mask = d_in[3];
  const float* wq = (const float*)d_in[4];
  const float* bq = (const float*)d_in[5];
  const float* wk = (const float*)d_in[6];
  const float* bk = (const float*)d_in[7];
  const float* wv = (const float*)d_in[8];
  const float* bv = (const float*)d_in[9];
  const float* wo = (const float*)d_in[10];
  const float* bo = (const float*)d_in[11];
  const float* gamma = (const float*)d_in[12];
  const float* beta = (const float*)d_in[13];

  float* out = (float*)d_out;                            // (1,2048,1024)
  float* attn = out + (size_t)S_LEN * D_MID;             // (1,16,2048,2048)
  float* ctx2 = attn + (size_t)N_HEADS * S_LEN * S_LEN;  // (2048,1,1024)

  // ws map (<= 28 MB, proven by R4):
  //  0-4 qb | 4-8 kbuf | 8-12 vbuf | 12-16 vbt
  //  16-16.5 bits | 16.5-17 lpart | 17.25-17.375 linv
  //  18-20 wqb, 20-22 wkb, 22-24 wvb (dead after gemm_proj)
  //  18-26 ctxp (written by attn_main after weights dead)
  //  26-28 wob (live until gemm_out)
  //  preLN aliases 0-8 (qb/kbuf dead by gemm_out time)
  unsigned char* ws = (unsigned char*)d_ws;
  unsigned short* qb   = (unsigned short*)(ws);
  unsigned short* kbuf = (unsigned short*)(ws + (size_t)(4 << 20));
  unsigned short* vbuf = (unsigned short*)(ws + (size_t)(8 << 20));
  unsigned short* vbt  = (unsigned short*)(ws + (size_t)(12 << 20));
  unsigned long long* bits = (unsigned long long*)(ws + (size_t)(16 << 20));
  float* lpart = (float*)(ws + (size_t)(16 << 20) + 524288);
  float* linv  = (float*)(ws + (size_t)(17 << 20) + 262144);
  unsigned short* wqb = (unsigned short*)(ws + (size_t)(18 << 20));
  unsigned short* wkb = (unsigned short*)(ws + (size_t)(20 << 20));
  unsigned short* wvb = (unsigned short*)(ws + (size_t)(22 << 20));
  unsigned short* ctxp = (unsigned short*)(ws + (size_t)(18 << 20));
  unsigned short* wob = (unsigned short*)(ws + (size_t)(26 << 20));
  float* preLN = (float*)(ws);

  CvtP cw;
  cw.s[0] = wq; cw.d[0] = wqb;
  cw.s[1] = wk; cw.d[1] = wkb;
  cw.s[2] = wv; cw.d[2] = wvb;
  cw.s[3] = wo; cw.d[3] = wob;
  cvt_w<<<2048, 256, 0, stream>>>(cw);

  ProjParams pp;
  pp.A[0] = Q;  pp.W[0] = wqb; pp.Bi[0] = bq; pp.O[0] = qb;
  pp.A[1] = K;  pp.W[1] = wkb; pp.Bi[1] = bk; pp.O[1] = kbuf;
  pp.A[2] = V;  pp.W[2] = wvb; pp.Bi[2] = bv; pp.O[2] = vbuf;

  gemm_proj<<<dim3(D_MID / 128, S_LEN / 128, 3), 256, 0, stream>>>(pp);
  pack_mask<<<256, 256, 0, stream>>>(mask, bits);
  transpose_to_vbt<<<dim3(S_LEN / 64, D_MID / 64), 256, 0, stream>>>(vbuf, vbt);
  lsum_kernel<<<2048, 256, 0, stream>>>(qb, kbuf, bits, lpart);
  lcombine<<<128, 256, 0, stream>>>(lpart, linv);
  attn_main<<<1024, 256, 0, stream>>>(qb, kbuf, vbt, bits, linv, attn, ctxp);
  ctx_reduce<<<(S_LEN * D_MID / 4) / 256, 256, 0, stream>>>(ctxp, ctx2);
  gemm_out<<<dim3(D_MID / 128, S_LEN / 128), 256, 0, stream>>>(ctx2, wob, bo, Q, preLN);
  layernorm_k<<<S_LEN, 256, 0, stream>>>(preLN, gamma, beta, out);
}

// Round 14
// 230.294 us; speedup vs baseline: 1.1620x; 1.1620x over previous
//
#include <hip/hip_runtime.h>
#include <stdint.h>

#define S_LEN 2048
#define D_MID 1024
#define N_HEADS 16
#define D_HEAD 64

typedef __attribute__((ext_vector_type(4))) float f32x4;
typedef __attribute__((ext_vector_type(8))) short bf16x8;

__device__ __forceinline__ unsigned short f2bf(float x) {
  unsigned int u = __builtin_bit_cast(unsigned int, x);
  u += 0x7fffu + ((u >> 16) & 1u);
  return (unsigned short)(u >> 16);
}
__device__ __forceinline__ float bf2f(unsigned short h) {
  unsigned int u = ((unsigned int)h) << 16;
  return __builtin_bit_cast(float, u);
}
__device__ __forceinline__ unsigned int pack2(float x, float y) {
  return (unsigned int)f2bf(x) | ((unsigned int)f2bf(y) << 16);
}
__device__ __forceinline__ bf16x8 pack8(f32x4 a, f32x4 b) {
  uint4 u;
  u.x = pack2(a.x, a.y); u.y = pack2(a.z, a.w);
  u.z = pack2(b.x, b.y); u.w = pack2(b.z, b.w);
  return __builtin_bit_cast(bf16x8, u);
}
// HW packed fp32->bf16 (RNE, identical rounding to f2bf) — GEMM staging only
__device__ __forceinline__ unsigned int cvtpk(float lo, float hi) {
  unsigned int r;
  asm("v_cvt_pk_bf16_f32 %0, %1, %2" : "=v"(r) : "v"(lo), "v"(hi));
  return r;
}

#define MFMA16(a, b, c) __builtin_amdgcn_mfma_f32_16x16x32_bf16((a), (b), (c), 0, 0, 0)

// ---------------------------------------------------------------------------
// cvt_w: fp32 -> bf16 for 4 weight matrices (1M elems each)
// ---------------------------------------------------------------------------
struct CvtP {
  const float* s[4];
  unsigned short* d[4];
};
__global__ __launch_bounds__(256) void cvt_w(CvtP P) {
  const int t = blockIdx.x * 256 + threadIdx.x;  // 0..524287
  const int seg = t >> 17;                       // 131072 threads/segment
  const int off = (t & 131071) * 8;
  const float* s = P.s[seg] + off;
  f32x4 x = *(const f32x4*)s, y = *(const f32x4*)(s + 4);
  uint4 u;
  u.x = cvtpk(x.x, x.y); u.y = cvtpk(x.z, x.w);
  u.z = cvtpk(y.x, y.y); u.w = cvtpk(y.z, y.w);
  *(uint4*)(P.d[seg] + off) = u;
}

// ---------------------------------------------------------------------------
// Projection GEMM: C = A(f32, MxK) * W^T(bf16, NxK) + bias, output bf16.
// 128x128 tile, BK=64, padded [128][72] LDS (no swizzle).
// ---------------------------------------------------------------------------
struct ProjParams {
  const float* A[3];
  const unsigned short* W[3];
  const float* Bi[3];
  unsigned short* O[3];
};

__global__ __launch_bounds__(256) void gemm_proj(ProjParams P) {
  const int z = blockIdx.z;
  const float* __restrict__ A = P.A[z];
  const unsigned short* __restrict__ W = P.W[z];
  const float* __restrict__ bias = P.Bi[z];
  unsigned short* __restrict__ O = P.O[z];

  __shared__ __align__(16) unsigned short As[128][72];
  __shared__ __align__(16) unsigned short Bs[128][72];

  const int tid = threadIdx.x;
  const int lane = tid & 63, w = tid >> 6;
  const int wm = w >> 1, wn = w & 1;
  const int l15 = lane & 15, lhi = lane >> 4;
  const int m0 = blockIdx.y * 128, n0 = blockIdx.x * 128;
  const int sr = tid >> 1, sc = (tid & 1) * 32;

  f32x4 acc[4][4] = {};

  for (int k0 = 0; k0 < D_MID; k0 += 64) {
    __syncthreads();
    {
      const float* a = A + (size_t)(m0 + sr) * D_MID + k0 + sc;
      const unsigned short* b = W + (size_t)(n0 + sr) * D_MID + k0 + sc;
#pragma unroll
      for (int q = 0; q < 4; ++q) {
        f32x4 x = ((const f32x4*)a)[2 * q];
        f32x4 y = ((const f32x4*)a)[2 * q + 1];
        uint4 u;
        u.x = cvtpk(x.x, x.y); u.y = cvtpk(x.z, x.w);
        u.z = cvtpk(y.x, y.y); u.w = cvtpk(y.z, y.w);
        *(uint4*)&As[sr][sc + q * 8] = u;
        *(uint4*)&Bs[sr][sc + q * 8] = ((const uint4*)b)[q];
      }
    }
    __syncthreads();

    bf16x8 af[4][2], bfr[4][2];
#pragma unroll
    for (int a2 = 0; a2 < 4; ++a2) {
      af[a2][0] = *(const bf16x8*)&As[wm * 64 + a2 * 16 + l15][lhi * 8];
      af[a2][1] = *(const bf16x8*)&As[wm * 64 + a2 * 16 + l15][32 + lhi * 8];
      bfr[a2][0] = *(const bf16x8*)&Bs[wn * 64 + a2 * 16 + l15][lhi * 8];
      bfr[a2][1] = *(const bf16x8*)&Bs[wn * 64 + a2 * 16 + l15][32 + lhi * 8];
    }
#pragma unroll
    for (int a2 = 0; a2 < 4; ++a2)
#pragma unroll
      for (int b2 = 0; b2 < 4; ++b2) {
        acc[a2][b2] = MFMA16(af[a2][0], bfr[b2][0], acc[a2][b2]);
        acc[a2][b2] = MFMA16(af[a2][1], bfr[b2][1], acc[a2][b2]);
      }
  }

#pragma unroll
  for (int a2 = 0; a2 < 4; ++a2)
#pragma unroll
    for (int b2 = 0; b2 < 4; ++b2) {
      const int col = n0 + wn * 64 + b2 * 16 + l15;
      const float bv = bias[col];
#pragma unroll
      for (int j = 0; j < 4; ++j) {
        const int row = m0 + wm * 64 + a2 * 16 + lhi * 4 + j;
        O[(size_t)row * D_MID + col] = f2bf(acc[a2][b2][j] + bv);
      }
    }
}

// ---------------------------------------------------------------------------
// Output GEMM: preLN = ctx(f32, MxK) * wo^T(bf16, NxK) + bo + Q (residual).
// ---------------------------------------------------------------------------
__global__ __launch_bounds__(256) void gemm_out(
    const float* __restrict__ Actx, const unsigned short* __restrict__ W,
    const float* __restrict__ bias, const float* __restrict__ resid,
    float* __restrict__ Of) {
  __shared__ __align__(16) unsigned short As[128][72];
  __shared__ __align__(16) unsigned short Bs[128][72];

  const int tid = threadIdx.x;
  const int lane = tid & 63, w = tid >> 6;
  const int wm = w >> 1, wn = w & 1;
  const int l15 = lane & 15, lhi = lane >> 4;
  const int m0 = blockIdx.y * 128, n0 = blockIdx.x * 128;
  const int sr = tid >> 1, sc = (tid & 1) * 32;

  f32x4 acc[4][4] = {};

  for (int k0 = 0; k0 < D_MID; k0 += 64) {
    __syncthreads();
    {
      const float* a = Actx + (size_t)(m0 + sr) * D_MID + k0 + sc;
      const unsigned short* b = W + (size_t)(n0 + sr) * D_MID + k0 + sc;
#pragma unroll
      for (int q = 0; q < 4; ++q) {
        f32x4 x = ((const f32x4*)a)[2 * q];
        f32x4 y = ((const f32x4*)a)[2 * q + 1];
        uint4 u;
        u.x = cvtpk(x.x, x.y); u.y = cvtpk(x.z, x.w);
        u.z = cvtpk(y.x, y.y); u.w = cvtpk(y.z, y.w);
        *(uint4*)&As[sr][sc + q * 8] = u;
        *(uint4*)&Bs[sr][sc + q * 8] = ((const uint4*)b)[q];
      }
    }
    __syncthreads();

    bf16x8 af[4][2], bfr[4][2];
#pragma unroll
    for (int a2 = 0; a2 < 4; ++a2) {
      af[a2][0] = *(const bf16x8*)&As[wm * 64 + a2 * 16 + l15][lhi * 8];
      af[a2][1] = *(const bf16x8*)&As[wm * 64 + a2 * 16 + l15][32 + lhi * 8];
      bfr[a2][0] = *(const bf16x8*)&Bs[wn * 64 + a2 * 16 + l15][lhi * 8];
      bfr[a2][1] = *(const bf16x8*)&Bs[wn * 64 + a2 * 16 + l15][32 + lhi * 8];
    }
#pragma unroll
    for (int a2 = 0; a2 < 4; ++a2)
#pragma unroll
      for (int b2 = 0; b2 < 4; ++b2) {
        acc[a2][b2] = MFMA16(af[a2][0], bfr[b2][0], acc[a2][b2]);
        acc[a2][b2] = MFMA16(af[a2][1], bfr[b2][1], acc[a2][b2]);
      }
  }

#pragma unroll
  for (int a2 = 0; a2 < 4; ++a2)
#pragma unroll
    for (int b2 = 0; b2 < 4; ++b2) {
      const int col = n0 + wn * 64 + b2 * 16 + l15;
      const float bv = bias[col];
#pragma unroll
      for (int j = 0; j < 4; ++j) {
        const int row = m0 + wm * 64 + a2 * 16 + lhi * 4 + j;
        Of[(size_t)row * D_MID + col] =
            acc[a2][b2][j] + bv + resid[(size_t)row * D_MID + col];
      }
    }
}

// ---------------------------------------------------------------------------
// bf16 transpose: v[2048][1024] -> vt[1024][2048]
// ---------------------------------------------------------------------------
__global__ __launch_bounds__(256) void transpose_to_vbt(
    const unsigned short* __restrict__ v, unsigned short* __restrict__ vt) {
  __shared__ __align__(16) unsigned short t[64][72];
  const int tid = threadIdx.x;
  const int bs = blockIdx.x * 64;
  const int bd = blockIdx.y * 64;
  {
    const int r = tid >> 2, c = (tid & 3) * 16;
    const unsigned short* src = v + (size_t)(bs + r) * D_MID + bd + c;
    *(uint4*)&t[r][c] = *(const uint4*)src;
    *(uint4*)&t[r][c + 8] = *(const uint4*)(src + 8);
  }
  __syncthreads();
  {
    const int d = tid >> 2, c = (tid & 3) * 16;
    unsigned int u[8];
#pragma unroll
    for (int jj = 0; jj < 8; ++jj)
      u[jj] = (unsigned int)t[c + 2 * jj][d] | ((unsigned int)t[c + 2 * jj + 1][d] << 16);
    uint4 w0, w1;
    w0.x = u[0]; w0.y = u[1]; w0.z = u[2]; w0.w = u[3];
    w1.x = u[4]; w1.y = u[5]; w1.z = u[6]; w1.w = u[7];
    unsigned short* dst = vt + (size_t)(bd + d) * S_LEN + bs + c;
    *(uint4*)dst = w0;
    *(uint4*)(dst + 8) = w1;
  }
}

// ---------------------------------------------------------------------------
// Mask -> keep-bitmask uint64[2048][32]  (bit k = attend). Auto-detect dtype.
// ---------------------------------------------------------------------------
__global__ __launch_bounds__(256) void pack_mask(const void* __restrict__ maskp,
                                                 unsigned long long* __restrict__ bits) {
  __shared__ int s_m32;
  if (threadIdx.x == 0) s_m32 = 1;
  __syncthreads();
  {
    const unsigned char* m8d = (const unsigned char*)maskp;
    bool nz = false;
    for (int i = threadIdx.x; i < 4096; i += 256)
      if (i & 3) nz |= (m8d[i] != 0);
    if (nz) s_m32 = 0;  // benign race: all writers store 0
  }
  __syncthreads();

  const int wi = blockIdx.x * 256 + threadIdx.x;  // 0..65535
  const int row = wi >> 5, chunk = wi & 31;
  unsigned long long keep = 0ull;
  if (s_m32) {
    const int* mi = (const int*)maskp + (size_t)row * S_LEN + chunk * 64;
#pragma unroll
    for (int q = 0; q < 16; ++q) {
      int4 v = ((const int4*)mi)[q];
      const int b = q * 4;
      if (!v.x) keep |= 1ull << b;
      if (!v.y) keep |= 1ull << (b + 1);
      if (!v.z) keep |= 1ull << (b + 2);
      if (!v.w) keep |= 1ull << (b + 3);
    }
  } else {
    const unsigned char* p = (const unsigned char*)maskp + (size_t)row * S_LEN + chunk * 64;
    union { uint4 v[4]; unsigned char c[64]; } u;
#pragma unroll
    for (int q = 0; q < 4; ++q) u.v[q] = ((const uint4*)p)[q];
#pragma unroll
    for (int b = 0; b < 64; ++b)
      if (!u.c[b]) keep |= 1ull << b;
  }
  bits[wi] = keep;
}

// ---------------------------------------------------------------------------
// lsum: l_part[kc][head][q] = sum_{k in chunk} exp(s)*keep   (max = 0)
// LDS-staged K, reg prefetch, hoisted lane-reduce. [R8-verbatim]
// ---------------------------------------------------------------------------
__global__ __launch_bounds__(256) void lsum_kernel(
    const unsigned short* __restrict__ qb, const unsigned short* __restrict__ kb,
    const unsigned long long* __restrict__ bits, float* __restrict__ lpart) {
  const int bid = blockIdx.x;
  const int head = bid & 15;
  const int r = bid >> 4;  // 0..127
  const int q0 = (r & 31) * 64;
  const int kc = r >> 5;  // 0..3
  const int k0 = kc * (S_LEN / 4);

  const int tid = threadIdx.x;
  const int lane = tid & 63, w = tid >> 6;
  const int l15 = lane & 15, lhi = lane >> 4;

  __shared__ __align__(16) unsigned short Kt[64][72];

  bf16x8 aq[2];
  {
    const unsigned short* qp =
        qb + (size_t)(q0 + w * 16 + l15) * D_MID + head * D_HEAD + lhi * 8;
    aq[0] = *(const bf16x8*)qp;
    aq[1] = *(const bf16x8*)(qp + 32);
  }

  float plrow[4] = {0.f, 0.f, 0.f, 0.f};
  const int sk = tid >> 2, sc = (tid & 3) * 16;

  const int ntiles = (S_LEN / 4) / 64;  // 8
  uint4 kr0, kr1;
  {
    const unsigned short* src = kb + (size_t)(k0 + sk) * D_MID + head * D_HEAD + sc;
    kr0 = *(const uint4*)src;
    kr1 = *(const uint4*)(src + 8);
  }

  for (int t = 0; t < ntiles; ++t) {
    const int kt = k0 + t * 64;
    __syncthreads();
    *(uint4*)&Kt[sk][sc] = kr0;
    *(uint4*)&Kt[sk][sc + 8] = kr1;
    __syncthreads();
    if (t + 1 < ntiles) {
      const unsigned short* src =
          kb + (size_t)(kt + 64 + sk) * D_MID + head * D_HEAD + sc;
      kr0 = *(const uint4*)src;
      kr1 = *(const uint4*)(src + 8);
    }

    f32x4 sacc[4];
#pragma unroll
    for (int a = 0; a < 4; ++a) {
      bf16x8 b0 = *(const bf16x8*)&Kt[a * 16 + l15][lhi * 8];
      bf16x8 b1 = *(const bf16x8*)&Kt[a * 16 + l15][32 + lhi * 8];
      f32x4 t2 = {0.f, 0.f, 0.f, 0.f};
      t2 = MFMA16(aq[0], b0, t2);
      t2 = MFMA16(aq[1], b1, t2);
      sacc[a] = t2;
    }

#pragma unroll
    for (int j = 0; j < 4; ++j) {
      const int qg = q0 + w * 16 + lhi * 4 + j;
      const unsigned long long w64 = bits[(size_t)qg * 32 + (kt >> 6)];
#pragma unroll
      for (int a = 0; a < 4; ++a) {
        const float keep = (float)((w64 >> (a * 16 + l15)) & 1ull);
        plrow[j] += __expf(sacc[a][j] * 0.125f) * keep;
      }
    }
  }

#pragma unroll
  for (int j = 0; j < 4; ++j) {
    float ts = plrow[j];
#pragma unroll
    for (int off = 1; off < 16; off <<= 1) ts += __shfl_xor(ts, off);
    plrow[j] = ts;
  }
  if (l15 == 0) {
#pragma unroll
    for (int j = 0; j < 4; ++j) {
      const int qg = q0 + w * 16 + lhi * 4 + j;
      lpart[((size_t)kc * N_HEADS + head) * S_LEN + qg] = plrow[j];
    }
  }
}

__global__ __launch_bounds__(256) void lcombine(const float* __restrict__ lpart,
                                                float* __restrict__ linv) {
  const int i = blockIdx.x * 256 + threadIdx.x;  // 0..32767
  const float s = lpart[i] + lpart[32768 + i] + lpart[65536 + i] + lpart[98304 + i];
  linv[i] = (s > 0.f) ? 1.f / s : 0.f;
}

// ---------------------------------------------------------------------------
// attn_main [R8-verbatim]: single pass, normalized P write (fp32 LDS -> nt
// dwordx4 stores) + PV. Reg-prefetch K/V. k-split nkc=2, bf16 ctx partials.
// ---------------------------------------------------------------------------
__global__ __launch_bounds__(256) void attn_main(
    const unsigned short* __restrict__ qb, const unsigned short* __restrict__ kb,
    const unsigned short* __restrict__ vbt, const unsigned long long* __restrict__ bits,
    const float* __restrict__ linv, float* __restrict__ attn_out,
    unsigned short* __restrict__ ctxp, int nkc) {
  const int bid = blockIdx.x;
  const int head = bid & 15;
  const int r = bid >> 4;
  const int q0 = (r & 31) * 64;
  const int kc = r >> 5;
  const int kspan = S_LEN / nkc;
  const int k_begin = kc * kspan;

  const int tid = threadIdx.x;
  const int lane = tid & 63, w = tid >> 6;
  const int l15 = lane & 15, lhi = lane >> 4;

  __shared__ __align__(16) unsigned short Kt[64][72];  // [key][dk]
  __shared__ __align__(16) unsigned short Vt[64][72];  // [d][key]
  __shared__ __align__(16) float PF[4][16][68];        // per-wave P (fp32)

  bf16x8 aq[2];
  float li[4];
  {
    const int qrow = q0 + w * 16 + l15;
    const unsigned short* qp = qb + (size_t)qrow * D_MID + head * D_HEAD + lhi * 8;
    aq[0] = *(const bf16x8*)qp;
    aq[1] = *(const bf16x8*)(qp + 32);
#pragma unroll
    for (int j = 0; j < 4; ++j)
      li[j] = linv[head * S_LEN + q0 + w * 16 + lhi * 4 + j];
  }

  f32x4 cacc[4] = {};
  const int sk = tid >> 2, sc = (tid & 3) * 16;
  const int ntiles = kspan / 64;

  uint4 kr0, kr1, vr0, vr1;
  {
    const unsigned short* srck = kb + (size_t)(k_begin + sk) * D_MID + head * D_HEAD + sc;
    kr0 = *(const uint4*)srck;
    kr1 = *(const uint4*)(srck + 8);
    const unsigned short* srcv = vbt + (size_t)(head * D_HEAD + sk) * S_LEN + k_begin + sc;
    vr0 = *(const uint4*)srcv;
    vr1 = *(const uint4*)(srcv + 8);
  }

  for (int t = 0; t < ntiles; ++t) {
    const int kt = k_begin + t * 64;
    __syncthreads();
    *(uint4*)&Kt[sk][sc] = kr0;
    *(uint4*)&Kt[sk][sc + 8] = kr1;
    *(uint4*)&Vt[sk][sc] = vr0;
    *(uint4*)&Vt[sk][sc + 8] = vr1;
    __syncthreads();
    if (t + 1 < ntiles) {
      const int kn = kt + 64;
      const unsigned short* srck = kb + (size_t)(kn + sk) * D_MID + head * D_HEAD + sc;
      kr0 = *(const uint4*)srck;
      kr1 = *(const uint4*)(srck + 8);
      const unsigned short* srcv = vbt + (size_t)(head * D_HEAD + sk) * S_LEN + kn + sc;
      vr0 = *(const uint4*)srcv;
      vr1 = *(const uint4*)(srcv + 8);
    }

    f32x4 sacc[4];
#pragma unroll
    for (int a = 0; a < 4; ++a) {
      bf16x8 b0 = *(const bf16x8*)&Kt[a * 16 + l15][lhi * 8];
      bf16x8 b1 = *(const bf16x8*)&Kt[a * 16 + l15][32 + lhi * 8];
      f32x4 t2 = {0.f, 0.f, 0.f, 0.f};
      t2 = MFMA16(aq[0], b0, t2);
      t2 = MFMA16(aq[1], b1, t2);
      sacc[a] = t2;
    }

    // p -> PF (fp32, wave-local)
#pragma unroll
    for (int j = 0; j < 4; ++j) {
      const int qg = q0 + w * 16 + lhi * 4 + j;
      const unsigned long long w64 = bits[(size_t)qg * 32 + (kt >> 6)];
#pragma unroll
      for (int a = 0; a < 4; ++a) {
        const float keep = (float)((w64 >> (a * 16 + l15)) & 1ull);
        PF[w][lhi * 4 + j][a * 16 + l15] = __expf(sacc[a][j] * 0.125f) * keep * li[j];
      }
    }

    // coalesced nt stores: 4x dwordx4 per lane, 256B per 16-lane group
    {
      float* abase = attn_out + (size_t)head * S_LEN * S_LEN +
                     (size_t)(q0 + w * 16) * S_LEN + kt;
#pragma unroll
      for (int g = 0; g < 4; ++g) {
        const int row = g * 4 + lhi;
        f32x4 v = *(const f32x4*)&PF[w][row][l15 * 4];
        __builtin_nontemporal_store(v, (f32x4*)(abase + (size_t)row * S_LEN + l15 * 4));
      }
    }

    // PV: rebuild bf16 A-fragments from PF (same rounding as before)
    bf16x8 pa0 = pack8(*(const f32x4*)&PF[w][l15][lhi * 8],
                       *(const f32x4*)&PF[w][l15][lhi * 8 + 4]);
    bf16x8 pa1 = pack8(*(const f32x4*)&PF[w][l15][32 + lhi * 8],
                       *(const f32x4*)&PF[w][l15][36 + lhi * 8]);
#pragma unroll
    for (int n = 0; n < 4; ++n) {
      bf16x8 v0 = *(const bf16x8*)&Vt[n * 16 + l15][lhi * 8];
      bf16x8 v1 = *(const bf16x8*)&Vt[n * 16 + l15][32 + lhi * 8];
      cacc[n] = MFMA16(pa0, v0, cacc[n]);
      cacc[n] = MFMA16(pa1, v1, cacc[n]);
    }
  }

  unsigned short* cp = ctxp + (size_t)kc * S_LEN * D_MID;
#pragma unroll
  for (int n = 0; n < 4; ++n)
#pragma unroll
    for (int j = 0; j < 4; ++j) {
      const int qg = q0 + w * 16 + lhi * 4 + j;
      const int col = head * D_HEAD + n * 16 + l15;
      cp[(size_t)qg * D_MID + col] = f2bf(cacc[n][j]);
    }
}

// ---------------------------------------------------------------------------
// ctx_reduce: ctx2(fp32, d_out) = sum of bf16 partials
// ---------------------------------------------------------------------------
__global__ __launch_bounds__(256) void ctx_reduce(const unsigned short* __restrict__ ctxp,
                                                  float* __restrict__ ctx2, int nkc) {
  const int i = blockIdx.x * 256 + threadIdx.x;  // over 2M/4 ushort4
  ushort4 a = ((const ushort4*)ctxp)[i];
  float4 o;
  o.x = bf2f(a.x); o.y = bf2f(a.y); o.z = bf2f(a.z); o.w = bf2f(a.w);
  if (nkc == 2) {
    ushort4 b = ((const ushort4*)(ctxp + (size_t)S_LEN * D_MID))[i];
    o.x += bf2f(b.x); o.y += bf2f(b.y); o.z += bf2f(b.z); o.w += bf2f(b.w);
  }
  ((float4*)ctx2)[i] = o;
}

// ---------------------------------------------------------------------------
// Row LayerNorm
// ---------------------------------------------------------------------------
__global__ __launch_bounds__(256) void layernorm_k(
    const float* __restrict__ x, const float* __restrict__ gamma,
    const float* __restrict__ beta, float* __restrict__ out) {
  const int row = blockIdx.x;
  const int tid = threadIdx.x;
  float4 v = ((const float4*)(x + (size_t)row * D_MID))[tid];
  float s = v.x + v.y + v.z + v.w;
  float s2 = v.x * v.x + v.y * v.y + v.z * v.z + v.w * v.w;
#pragma unroll
  for (int off = 1; off < 64; off <<= 1) {
    s += __shfl_xor(s, off);
    s2 += __shfl_xor(s2, off);
  }
  __shared__ float ps[4], ps2[4];
  const int w = tid >> 6;
  if ((tid & 63) == 0) { ps[w] = s; ps2[w] = s2; }
  __syncthreads();
  s = ps[0] + ps[1] + ps[2] + ps[3];
  s2 = ps2[0] + ps2[1] + ps2[2] + ps2[3];
  const float mu = s * (1.0f / D_MID);
  const float var = s2 * (1.0f / D_MID) - mu * mu;
  const float inv = rsqrtf(var + 1e-5f);
  float4 g = ((const float4*)gamma)[tid];
  float4 b = ((const float4*)beta)[tid];
  float4 o;
  o.x = (v.x - mu) * inv * g.x + b.x;
  o.y = (v.y - mu) * inv * g.y + b.y;
  o.z = (v.z - mu) * inv * g.z + b.z;
  o.w = (v.w - mu) * inv * g.w + b.w;
  ((float4*)(out + (size_t)row * D_MID))[tid] = o;
}

// ---------------------------------------------------------------------------
extern "C" void kernel_launch(void* const* d_in, const int* in_sizes, int n_in,
                              void* d_out, int out_size, void* d_ws, size_t ws_size,
                              hipStream_t stream) {
  (void)in_sizes; (void)n_in; (void)out_size;
  const float* Q = (const float*)d_in[0];
  const float* K = (const float*)d_in[1];
  const float* V = (const float*)d_in[2];
  const void* mask = d_in[3];
  const float* wq = (const float*)d_in[4];
  const float* bq = (const float*)d_in[5];
  const float* wk = (const float*)d_in[6];
  const float* bk = (const float*)d_in[7];
  const float* wv = (const float*)d_in[8];
  const float* bv = (const float*)d_in[9];
  const float* wo = (const float*)d_in[10];
  const float* bo = (const float*)d_in[11];
  const float* gamma = (const float*)d_in[12];
  const float* beta = (const float*)d_in[13];

  float* out = (float*)d_out;                            // (1,2048,1024)
  float* attn = out + (size_t)S_LEN * D_MID;             // (1,16,2048,2048)
  float* ctx2 = attn + (size_t)N_HEADS * S_LEN * S_LEN;  // (2048,1,1024)

  // ws map (<= 28 MB, proven by R4):
  //  0-4 qb | 4-8 kbuf | 8-12 vbuf | 12-16 vbt
  //  16-16.5 bits | 16.5-17 lpart | 17.25-17.375 linv
  //  18-20 wqb, 20-22 wkb, 22-24 wvb (dead after gemm_proj)
  //  18-26 ctxp (written by attn_main after weights dead)
  //  26-28 wob (live until gemm_out)
  //  preLN aliases 0-8 (qb/kbuf dead by gemm_out time)
  unsigned char* ws = (unsigned char*)d_ws;
  unsigned short* qb   = (unsigned short*)(ws);
  unsigned short* kbuf = (unsigned short*)(ws + (size_t)(4 << 20));
  unsigned short* vbuf = (unsigned short*)(ws + (size_t)(8 << 20));
  unsigned short* vbt  = (unsigned short*)(ws + (size_t)(12 << 20));
  unsigned long long* bits = (unsigned long long*)(ws + (size_t)(16 << 20));
  float* lpart = (float*)(ws + (size_t)(16 << 20) + 524288);
  float* linv  = (float*)(ws + (size_t)(17 << 20) + 262144);
  unsigned short* wqb = (unsigned short*)(ws + (size_t)(18 << 20));
  unsigned short* wkb = (unsigned short*)(ws + (size_t)(20 << 20));
  unsigned short* wvb = (unsigned short*)(ws + (size_t)(22 << 20));
  unsigned short* ctxp = (unsigned short*)(ws + (size_t)(18 << 20));
  unsigned short* wob = (unsigned short*)(ws + (size_t)(26 << 20));
  float* preLN = (float*)(ws);

  const int nkc = 2;

  CvtP cw;
  cw.s[0] = wq; cw.d[0] = wqb;
  cw.s[1] = wk; cw.d[1] = wkb;
  cw.s[2] = wv; cw.d[2] = wvb;
  cw.s[3] = wo; cw.d[3] = wob;
  cvt_w<<<2048, 256, 0, stream>>>(cw);

  ProjParams pp;
  pp.A[0] = Q;  pp.W[0] = wqb; pp.Bi[0] = bq; pp.O[0] = qb;
  pp.A[1] = K;  pp.W[1] = wkb; pp.Bi[1] = bk; pp.O[1] = kbuf;
  pp.A[2] = V;  pp.W[2] = wvb; pp.Bi[2] = bv; pp.O[2] = vbuf;

  gemm_proj<<<dim3(D_MID / 128, S_LEN / 128, 3), 256, 0, stream>>>(pp);
  pack_mask<<<256, 256, 0, stream>>>(mask, bits);
  transpose_to_vbt<<<dim3(S_LEN / 64, D_MID / 64), 256, 0, stream>>>(vbuf, vbt);
  lsum_kernel<<<2048, 256, 0, stream>>>(qb, kbuf, bits, lpart);
  lcombine<<<128, 256, 0, stream>>>(lpart, linv);
  attn_main<<<512 * nkc, 256, 0, stream>>>(qb, kbuf, vbt, bits, linv, attn, ctxp, nkc);
  ctx_reduce<<<(S_LEN * D_MID / 4) / 256, 256, 0, stream>>>(ctxp, ctx2, nkc);
  gemm_out<<<dim3(D_MID / 128, S_LEN / 128), 256, 0, stream>>>(ctx2, wob, bo, Q, preLN);
  layernorm_k<<<S_LEN, 256, 0, stream>>>(preLN, gamma, beta, out);
}